// Round 7
// baseline (351.285 us; speedup 1.0000x reference)
//
#include <hip/hip_runtime.h>
#include <hip/hip_bf16.h>
#include <stdint.h>

// LSH: project -> sign-bit-pack -> Hamming via xor+popcount -> cos
// packed codes in d_ws: [12288 rows][16 u64]; word w holds bits w*64..+63,
// bit b of word = sign(dot(emb[row], r[w*64+b])). Identical bit order for
// u and v, so xor-popcount Hamming is exact.

#define NBITS   1024
#define NROWS1  4096
#define NROWS2  8192

// ---------------------------------------------------------------------------
// Kernel 1: projection + sign + pack.
// Balance law (per-CU): with both operands via LDS, VALU-bound needs
// RP >= 6(R+P) -> acc >= 144 regs -> spills (round 6: WRITE_SIZE 47 MB).
// Fix: E comes from GLOBAL via wave-uniform address (1 L1 transaction,
// VMEM pipe); only the r operand uses the LDS pipe -> condition relaxes to
// R >= 6. R=8 rows/wave, P=8 bit-planes/lane: acc[8][8]=64 regs, rv 32,
// ~170 total -> no spill at launch_bounds(256,2).
// Grid (384 rowBlks, 2 bitTiles), block 256 (4 waves).
// Block: 32 rows x 512 bits. Wave: 8 rows. Lane l: planes p*64+l (ballot
// yields u64 word p directly).
// r_lds [512 bits][8 float4] = 64 KB, slot-swizzled s^(bit&7) (k2's proven
// conflict-free pattern). E tile 32 rows x 512 B = 16 KB -> L1-resident.
// Per ks-step/wave: 8 swizzled b128 (96 LDS-cyc) + 8 uniform VMEM loads
// feed 256 wave-FMAs (512 SIMD-cyc) -> VALU-bound.
// VALU floor: 1.61G lane-FMA / 78.6T = 20.5 us.
// ---------------------------------------------------------------------------
__global__ __launch_bounds__(256, 2) void lsh_project_pack(
    const float4* __restrict__ emb1,
    const float4* __restrict__ emb2,
    const float4* __restrict__ r4,
    unsigned long long* __restrict__ packed)
{
  __shared__ float4 r_lds[512 * 8];    // 64 KB, [bit][slot ^ (bit&7)]

  const int t = threadIdx.x;
  const int w = t >> 6;                // wave 0..3
  const int l = t & 63;
  const int rowBlk  = blockIdx.x;      // 0..383 (32 rows each)
  const int bitTile = blockIdx.y;      // 0..1   (512 bits each)

  const int blockRow0 = rowBlk * 32;
  const bool side1    = blockRow0 < NROWS1;        // uniform (blockIdx-only)
  const float4* __restrict__ eb4 = side1 ? emb1 : emb2;
  const int rowOff = side1 ? blockRow0 : blockRow0 - NROWS1;

  float acc[8][8];
#pragma unroll
  for (int rr = 0; rr < 8; ++rr)
#pragma unroll
    for (int p = 0; p < 8; ++p) acc[rr][p] = 0.0f;

  const int key = l & 7;
  // wave-uniform E base (float4 units); w*8 is per-wave, rr/ks vary in-loop
  const size_t ebase = (size_t)(rowOff + w * 8) * 32;

  for (int ch = 0; ch < 4; ++ch) {
    __syncthreads();                   // previous chunk's rv reads done
    // stage r chunk: 512 bits x 8 float4, swizzled (16 writes/thread,
    // coalesced global reads, conflict-free LDS writes)
#pragma unroll
    for (int i = 0; i < 16; ++i) {
      const int idx = t + i * 256;
      const int bit = idx >> 3;
      const int s   = idx & 7;
      r_lds[bit * 8 + (s ^ (bit & 7))] =
          r4[(size_t)(bitTile * 512 + bit) * 32 + ch * 8 + s];
    }
    __syncthreads();

#pragma unroll
    for (int ks = 0; ks < 8; ++ks) {
      float4 rv[8];
#pragma unroll
      for (int p = 0; p < 8; ++p)
        rv[p] = r_lds[(p * 64 + l) * 8 + (ks ^ key)];   // conflict-free b128
#pragma unroll
      for (int rr = 0; rr < 8; ++rr) {
        // wave-uniform address -> single L1 transaction, VMEM pipe
        const float4 ev = eb4[ebase + (size_t)rr * 32 + ch * 8 + ks];
#pragma unroll
        for (int p = 0; p < 8; ++p) {
          acc[rr][p] = fmaf(ev.x, rv[p].x, acc[rr][p]);
          acc[rr][p] = fmaf(ev.y, rv[p].y, acc[rr][p]);
          acc[rr][p] = fmaf(ev.z, rv[p].z, acc[rr][p]);
          acc[rr][p] = fmaf(ev.w, rv[p].w, acc[rr][p]);
        }
      }
    }
  }

  // ballot-pack: 64 (rr,p) words park one-per-lane, then one store each
  unsigned long long keep = 0ull;
#pragma unroll
  for (int rr = 0; rr < 8; ++rr)
#pragma unroll
    for (int p = 0; p < 8; ++p) {
      const unsigned long long m = __ballot(acc[rr][p] > 0.0f);
      if (l == rr * 8 + p) keep = m;
    }
  const int row = blockRow0 + w * 8 + (l >> 3);   // lane l -> row rr=(l>>3)
  packed[(size_t)row * 16 + bitTile * 8 + (l & 7)] = keep;
}

// ---------------------------------------------------------------------------
// Kernel 2: Hamming (xor + popcount) + cos. EXACT round-3 code (measured
// 88.5 us, VALU 82%). Do not touch.
// Grid (32 n-blocks, 64 m-blocks), block 256 (4 waves).
// Block tile: 64 rows x 256 cols. Thread: 8 rows x 8 cols (2 DS reads/output).
// ---------------------------------------------------------------------------
__global__ __launch_bounds__(256, 3) void lsh_hamming_cos(
    const uint4* __restrict__ up,    // [4096][8]
    const uint4* __restrict__ vp,    // [8192][8]
    const float* __restrict__ pi_in,
    float* __restrict__ out)         // [4096][8192]
{
  __shared__ uint4 u_lds[64 * 8];    // 8 KB, linear
  __shared__ uint4 v_lds[256 * 8];   // 32 KB, swizzled

  const int t  = threadIdx.x;
  const int w  = t >> 6;
  const int l  = t & 63;
  const int n0 = blockIdx.x * 256;
  const int m0 = blockIdx.y * 64;

  // stage U tile (linear, coalesced)
#pragma unroll
  for (int i = 0; i < 2; ++i)
    u_lds[t + i * 256] = up[(size_t)m0 * 8 + t + i * 256];

  // stage V tile (swizzle uint4 slot: w4 -> w4 ^ ((col>>2)&7))
#pragma unroll
  for (int i = 0; i < 8; ++i) {
    const int idx = t + i * 256;
    const int col = idx >> 3;
    const int w4  = idx & 7;
    v_lds[col * 8 + (w4 ^ ((col >> 2) & 7))] = vp[(size_t)n0 * 8 + idx];
  }
  __syncthreads();

  int h[8][8];
#pragma unroll
  for (int r = 0; r < 8; ++r)
#pragma unroll
    for (int j = 0; j < 8; ++j) h[r][j] = 0;

  const int key  = l & 7;
  const int row0 = w * 16 + (l >> 5) * 8;   // thread's first row (block-local)
  const int c0   = (l & 31) * 4;            // thread's first col (block-local)

#pragma unroll
  for (int kk = 0; kk < 8; ++kk) {          // one uint4 (128 bits) per step
    uint4 U[8];
#pragma unroll
    for (int r = 0; r < 8; ++r)
      U[r] = u_lds[(row0 + r) * 8 + kk];    // 2-address broadcast: free
    const int slot = kk ^ key;
#pragma unroll
    for (int half = 0; half < 2; ++half) {
#pragma unroll
      for (int j = 0; j < 4; ++j) {
        const uint4 V = v_lds[(c0 + half * 128 + j) * 8 + slot];
#pragma unroll
        for (int r = 0; r < 8; ++r) {
          int s = h[r][half * 4 + j];
          s += __builtin_popcount(U[r].x ^ V.x);
          s += __builtin_popcount(U[r].y ^ V.y);
          s += __builtin_popcount(U[r].z ^ V.z);
          s += __builtin_popcount(U[r].w ^ V.w);
          h[r][half * 4 + j] = s;
        }
      }
    }
  }

  const float scale = pi_in[0] * (1.0f / (float)NBITS);

#pragma unroll
  for (int r = 0; r < 8; ++r) {
    const size_t row = (size_t)(m0 + row0 + r);
#pragma unroll
    for (int half = 0; half < 2; ++half) {
      float4 o;
      o.x = __cosf(scale * (float)h[r][half * 4 + 0]);
      o.y = __cosf(scale * (float)h[r][half * 4 + 1]);
      o.z = __cosf(scale * (float)h[r][half * 4 + 2]);
      o.w = __cosf(scale * (float)h[r][half * 4 + 3]);
      *(float4*)(out + row * NROWS2 + n0 + c0 + half * 128) = o;
    }
  }
}

// ---------------------------------------------------------------------------
extern "C" void kernel_launch(void* const* d_in, const int* in_sizes, int n_in,
                              void* d_out, int out_size, void* d_ws, size_t ws_size,
                              hipStream_t stream) {
  const float* emb1 = (const float*)d_in[0];   // [4096][128]
  const float* emb2 = (const float*)d_in[1];   // [8192][128]
  const float* r    = (const float*)d_in[2];   // [1024][128]
  const float* pi   = (const float*)d_in[3];   // [1]

  unsigned long long* packed = (unsigned long long*)d_ws;  // [12288][16]

  dim3 g1(384, 2), b1(256);
  lsh_project_pack<<<g1, b1, 0, stream>>>(
      (const float4*)emb1, (const float4*)emb2, (const float4*)r, packed);

  dim3 g2(32, 64), b2(256);
  lsh_hamming_cos<<<g2, b2, 0, stream>>>(
      (const uint4*)packed,
      (const uint4*)(packed + (size_t)NROWS1 * 16),
      pi, (float*)d_out);
}